// Round 2
// baseline (137.015 us; speedup 1.0000x reference)
//
#include <hip/hip_runtime.h>
#include <cstdint>
#include <cstddef>

typedef __bf16 bf16x8 __attribute__((ext_vector_type(8)));
typedef unsigned short u16x8 __attribute__((ext_vector_type(8)));
typedef float f32x4 __attribute__((ext_vector_type(4)));

#define MFMA(a, b, c) __builtin_amdgcn_mfma_f32_16x16x32_bf16(a, b, c, 0, 0, 0)

__device__ __forceinline__ unsigned short f2bfbits(float x) {
    unsigned u = __builtin_bit_cast(unsigned, x);
    u += 0x7FFFu + ((u >> 16) & 1u);           // round-to-nearest-even
    return (unsigned short)(u >> 16);
}

__device__ __forceinline__ bf16x8 pack8(f32x4 a, f32x4 b) {
    u16x8 t;
    t[0] = f2bfbits(a[0]); t[1] = f2bfbits(a[1]);
    t[2] = f2bfbits(a[2]); t[3] = f2bfbits(a[3]);
    t[4] = f2bfbits(b[0]); t[5] = f2bfbits(b[1]);
    t[6] = f2bfbits(b[2]); t[7] = f2bfbits(b[3]);
    return __builtin_bit_cast(bf16x8, t);
}

// ---------------------------------------------------------------------------
// Kernel 1: projections (unchanged from round 1).
// ---------------------------------------------------------------------------
__global__ __launch_bounds__(256) void proj_kernel(
    const float* __restrict__ q_data, const float* __restrict__ m_data,
    const float* __restrict__ Wq, const float* __restrict__ Wk,
    const float* __restrict__ Wv, const float* __restrict__ Wg,
    const float* __restrict__ bg,
    unsigned short* __restrict__ Qb, unsigned short* __restrict__ Kb,
    unsigned short* __restrict__ VT, float* __restrict__ gate)
{
    __shared__ unsigned short vt_lds[128][80];
    const int mat   = blockIdx.x >> 7;
    const int mtile = blockIdx.x & 127;
    const int wave  = threadIdx.x >> 6;
    const int lane  = threadIdx.x & 63;
    const int r16 = lane & 15, g = lane >> 4;
    const int rowbase = mtile * 64 + wave * 16;

    const float* src = (mat == 1 || mat == 2) ? m_data : q_data;
    const float* W   = (mat == 0) ? Wq : (mat == 1) ? Wk : (mat == 2) ? Wv : Wg;

    bf16x8 afrag[4];
    {
        const float* arow = src + (size_t)(rowbase + r16) * 128;
        #pragma unroll
        for (int kk = 0; kk < 4; ++kk) {
            f32x4 lo = *(const f32x4*)(arow + kk * 32 + g * 8);
            f32x4 hi = *(const f32x4*)(arow + kk * 32 + g * 8 + 4);
            afrag[kk] = pack8(lo, hi);
        }
    }

    f32x4 acc[8];
    #pragma unroll
    for (int n0 = 0; n0 < 8; ++n0) {
        f32x4 a = {0.f, 0.f, 0.f, 0.f};
        #pragma unroll
        for (int kk = 0; kk < 4; ++kk) {
            f32x4 lo, hi;
            #pragma unroll
            for (int i = 0; i < 4; ++i) {
                lo[i] = W[(size_t)(kk * 32 + g * 8 + i) * 128 + n0 * 16 + r16];
                hi[i] = W[(size_t)(kk * 32 + g * 8 + 4 + i) * 128 + n0 * 16 + r16];
            }
            a = MFMA(afrag[kk], pack8(lo, hi), a);
        }
        acc[n0] = a;
    }

    if (mat <= 1) {
        unsigned short* dst = (mat == 0) ? Qb : Kb;
        #pragma unroll
        for (int n0 = 0; n0 < 8; ++n0) {
            int n = n0 * 16 + r16, h = n >> 5, d = n & 31;
            #pragma unroll
            for (int i = 0; i < 4; ++i) {
                int grow = rowbase + 4 * g + i;
                int bb = grow >> 11, ns = grow & 2047;
                dst[(size_t)(bb * 4 + h) * 65536 + (size_t)ns * 32 + d] =
                    f2bfbits(acc[n0][i]);
            }
        }
    } else if (mat == 2) {
        #pragma unroll
        for (int n0 = 0; n0 < 8; ++n0) {
            int n = n0 * 16 + r16;
            #pragma unroll
            for (int i = 0; i < 4; ++i)
                vt_lds[n][wave * 16 + 4 * g + i] = f2bfbits(acc[n0][i]);
        }
        __syncthreads();
        int bb = rowbase >> 11;
        int nsbase = (mtile * 64) & 2047;
        #pragma unroll
        for (int it = 0; it < 4; ++it) {
            int idx = (threadIdx.x + it * 256) * 8;
            int n = idx >> 6, mm = idx & 63;
            u16x8 v = *(const u16x8*)&vt_lds[n][mm];
            *(u16x8*)(VT + (size_t)(bb * 128 + n) * 2048 + nsbase + mm) = v;
        }
    } else {
        #pragma unroll
        for (int n0 = 0; n0 < 8; ++n0) {
            int n = n0 * 16 + r16;
            float bgv = bg[n];
            #pragma unroll
            for (int i = 0; i < 4; ++i) {
                int grow = rowbase + 4 * g + i;
                float x = acc[n0][i] + bgv;
                gate[(size_t)grow * 128 + n] = 1.0f / (1.0f + __expf(-x));
            }
        }
    }
}

// ---------------------------------------------------------------------------
// Kernel 2: flash attention + gate + output GEMM.
// grid.x = B * 128 q-tiles; block = 1024 (16 waves = 4 heads x 4 kv-quarters).
// Each wave: swapped QK^T over its 512-wide kv quarter (8 iters of 64),
// bias/nbias prefetched one iteration ahead (HBM latency off the chain).
// Partials (m, l, acc) merged in LDS, then gate + @Wo + bo epilogue.
// ---------------------------------------------------------------------------
__global__ __launch_bounds__(1024) void attn_kernel(
    const unsigned short* __restrict__ Qb, const unsigned short* __restrict__ Kb,
    const unsigned short* __restrict__ VT, const float* __restrict__ gate,
    const float* __restrict__ bias, const float* __restrict__ nbias,
    const float* __restrict__ Wo, const float* __restrict__ bo,
    float* __restrict__ out)
{
    __shared__ char p_lds[16][2048];             // per-wave P tile 16x64 bf16
    __shared__ float comb_acc[16][16][33];       // per-wave partial acc (padded)
    __shared__ float comb_ml[16][2][16];         // per-wave partial m, l
    __shared__ unsigned short wa_lds[16][136];   // gated wa, padded rows

    const int b  = blockIdx.x >> 7;
    const int qb = (blockIdx.x & 127) * 16;
    const int w    = threadIdx.x >> 6;
    const int h    = w & 3;          // head
    const int p    = w >> 2;         // kv quarter
    const int lane = threadIdx.x & 63;
    const int q16 = lane & 15, g = lane >> 4;

    const size_t bh = (size_t)(b * 4 + h);
    const unsigned short* Qp = Qb + bh * 65536;
    const unsigned short* Kp = Kb + bh * 65536;
    const unsigned short* Vp = VT + bh * 65536;
    bf16x8 qfrag = *(const bf16x8*)(Qp + (size_t)(qb + q16) * 32 + g * 8);
    const float* brow = bias  + ((size_t)b * 2048 + qb + q16) * 2048;
    const float* nrow = nbias + ((size_t)h * 2048 + qb + q16) * 2048;
    char* pw = p_lds[w];
    const int swz = (q16 & 7) << 4;
    const int kv0 = p * 512;

    float m = -1e30f, ls = 0.f;
    f32x4 acc0 = {0, 0, 0, 0}, acc1 = {0, 0, 0, 0};

    // bias prefetch buffers (the only HBM-latency loads in the loop)
    f32x4 bb[4], nn[4];
    #pragma unroll
    for (int t = 0; t < 4; ++t) {
        bb[t] = *(const f32x4*)(brow + kv0 + t * 16 + g * 4);
        nn[t] = *(const f32x4*)(nrow + kv0 + t * 16 + g * 4);
    }

    #pragma unroll 2
    for (int it = 0; it < 8; ++it) {
        const int kb = kv0 + it * 64;
        // ---- QK^T (swapped): lane owns S[k=4g+i + 16t][q=q16] ----
        f32x4 s[4];
        #pragma unroll
        for (int t = 0; t < 4; ++t) {
            bf16x8 kf = *(const bf16x8*)(Kp + (size_t)(kb + t * 16 + q16) * 32 + g * 8);
            f32x4 z = {0, 0, 0, 0};
            s[t] = MFMA(kf, qfrag, z);
        }
        #pragma unroll
        for (int t = 0; t < 4; ++t) s[t] += bb[t] + nn[t];

        // ---- prefetch bias for next iteration ----
        if (it < 7) {
            #pragma unroll
            for (int t = 0; t < 4; ++t) {
                bb[t] = *(const f32x4*)(brow + kb + 64 + t * 16 + g * 4);
                nn[t] = *(const f32x4*)(nrow + kb + 64 + t * 16 + g * 4);
            }
        }

        // ---- online softmax ----
        float mx = -1e30f;
        #pragma unroll
        for (int t = 0; t < 4; ++t)
            mx = fmaxf(mx, fmaxf(fmaxf(s[t][0], s[t][1]), fmaxf(s[t][2], s[t][3])));
        mx = fmaxf(mx, __shfl_xor(mx, 16));
        mx = fmaxf(mx, __shfl_xor(mx, 32));
        float m_new = fmaxf(m, mx);
        float alpha = __expf(m - m_new);
        float psum = 0.f;
        #pragma unroll
        for (int t = 0; t < 4; ++t) {
            #pragma unroll
            for (int i = 0; i < 4; ++i) {
                float pv = __expf(s[t][i] - m_new);
                s[t][i] = pv;
                psum += pv;
            }
        }
        psum += __shfl_xor(psum, 16);
        psum += __shfl_xor(psum, 32);
        ls = ls * alpha + psum;
        m = m_new;

        // ---- stage P (bf16) into swizzled per-wave LDS ----
        #pragma unroll
        for (int t = 0; t < 4; ++t) {
            uint2 pk;
            pk.x = (unsigned)f2bfbits(s[t][0]) | ((unsigned)f2bfbits(s[t][1]) << 16);
            pk.y = (unsigned)f2bfbits(s[t][2]) | ((unsigned)f2bfbits(s[t][3]) << 16);
            *(uint2*)(pw + ((q16 * 128 + t * 32 + g * 8) ^ swz)) = pk;
        }

        // ---- rescale accumulators (rows 4g+i) ----
        float al0 = __shfl(alpha, 4 * g + 0);
        float al1 = __shfl(alpha, 4 * g + 1);
        float al2 = __shfl(alpha, 4 * g + 2);
        float al3 = __shfl(alpha, 4 * g + 3);
        acc0[0] *= al0; acc0[1] *= al1; acc0[2] *= al2; acc0[3] *= al3;
        acc1[0] *= al0; acc1[1] *= al1; acc1[2] *= al2; acc1[3] *= al3;

        // ---- PV ----
        #pragma unroll
        for (int c = 0; c < 2; ++c) {
            bf16x8 pa = *(const bf16x8*)(pw + ((q16 * 128 + c * 64 + g * 16) ^ swz));
            bf16x8 v0 = *(const bf16x8*)(Vp + (size_t)q16 * 2048 + kb + c * 32 + g * 8);
            bf16x8 v1 = *(const bf16x8*)(Vp + (size_t)(16 + q16) * 2048 + kb + c * 32 + g * 8);
            acc0 = MFMA(pa, v0, acc0);
            acc1 = MFMA(pa, v1, acc1);
        }
    }

    // ---- write partials to LDS ----
    #pragma unroll
    for (int i = 0; i < 4; ++i) {
        comb_acc[w][4 * g + i][q16]      = acc0[i];
        comb_acc[w][4 * g + i][16 + q16] = acc1[i];
    }
    if (g == 0) { comb_ml[w][0][q16] = m; comb_ml[w][1][q16] = ls; }
    __syncthreads();

    // ---- merge 4 kv-quarter partials (waves 0-3, head h=w) ----
    if (p == 0) {
        float m0 = comb_ml[h][0][q16],      m1 = comb_ml[4 + h][0][q16];
        float m2 = comb_ml[8 + h][0][q16],  m3 = comb_ml[12 + h][0][q16];
        float M = fmaxf(fmaxf(m0, m1), fmaxf(m2, m3));
        float e0 = __expf(m0 - M), e1 = __expf(m1 - M);
        float e2 = __expf(m2 - M), e3 = __expf(m3 - M);
        float L = comb_ml[h][1][q16] * e0 + comb_ml[4 + h][1][q16] * e1
                + comb_ml[8 + h][1][q16] * e2 + comb_ml[12 + h][1][q16] * e3;
        float invL = 1.0f / L;
        const float* grow = gate + ((size_t)b * 2048 + qb + q16) * 128 + h * 32;
        #pragma unroll
        for (int c = 0; c < 8; ++c) {
            int d = g * 8 + c;
            float o = comb_acc[h][q16][d] * e0 + comb_acc[4 + h][q16][d] * e1
                    + comb_acc[8 + h][q16][d] * e2 + comb_acc[12 + h][q16][d] * e3;
            o = o * invL * grow[d];
            wa_lds[q16][h * 32 + d] = f2bfbits(o);
        }
    }
    __syncthreads();

    // ---- out = wa @ Wo + bo; waves 0-3 compute cols [32w, 32w+32) ----
    if (w < 4) {
        f32x4 o0 = {0, 0, 0, 0}, o1 = {0, 0, 0, 0};
        #pragma unroll
        for (int kk = 0; kk < 4; ++kk) {
            bf16x8 a = *(const bf16x8*)&wa_lds[q16][kk * 32 + g * 8];
            f32x4 l0, h0, l1, h1;
            #pragma unroll
            for (int i = 0; i < 4; ++i) {
                int k0 = kk * 32 + g * 8 + i;
                int k1 = k0 + 4;
                l0[i] = Wo[(size_t)k0 * 128 + h * 32 + q16];
                h0[i] = Wo[(size_t)k1 * 128 + h * 32 + q16];
                l1[i] = Wo[(size_t)k0 * 128 + h * 32 + 16 + q16];
                h1[i] = Wo[(size_t)k1 * 128 + h * 32 + 16 + q16];
            }
            o0 = MFMA(a, pack8(l0, h0), o0);
            o1 = MFMA(a, pack8(l1, h1), o1);
        }
        float bo0 = bo[h * 32 + q16], bo1 = bo[h * 32 + 16 + q16];
        #pragma unroll
        for (int i = 0; i < 4; ++i) {
            int row = qb + 4 * g + i;
            out[((size_t)b * 2048 + row) * 128 + h * 32 + q16]      = o0[i] + bo0;
            out[((size_t)b * 2048 + row) * 128 + h * 32 + 16 + q16] = o1[i] + bo1;
        }
    }
}

// ---------------------------------------------------------------------------
extern "C" void kernel_launch(void* const* d_in, const int* in_sizes, int n_in,
                              void* d_out, int out_size, void* d_ws, size_t ws_size,
                              hipStream_t stream)
{
    const float* q_data = (const float*)d_in[0];
    const float* m_data = (const float*)d_in[1];
    const float* bias   = (const float*)d_in[2];
    const float* nbias  = (const float*)d_in[3];
    const float* Wq     = (const float*)d_in[4];
    const float* Wk     = (const float*)d_in[5];
    const float* Wv     = (const float*)d_in[6];
    const float* Wg     = (const float*)d_in[7];
    const float* bg     = (const float*)d_in[8];
    const float* Wo     = (const float*)d_in[9];
    const float* bo     = (const float*)d_in[10];
    float* out = (float*)d_out;

    unsigned short* Qb = (unsigned short*)d_ws;          // 1M bf16 = 2MB
    unsigned short* Kb = Qb + (1 << 20);
    unsigned short* VT = Kb + (1 << 20);
    float* gate = (float*)(VT + (1 << 20));              // 4MB

    proj_kernel<<<dim3(512), dim3(256), 0, stream>>>(
        q_data, m_data, Wq, Wk, Wv, Wg, bg, Qb, Kb, VT, gate);
    attn_kernel<<<dim3(512), dim3(1024), 0, stream>>>(
        Qb, Kb, VT, gate, bias, nbias, Wo, bo, out);
}

// Round 3
// 118.883 us; speedup vs baseline: 1.1525x; 1.1525x over previous
//
#include <hip/hip_runtime.h>
#include <cstdint>
#include <cstddef>

typedef __bf16 bf16x8 __attribute__((ext_vector_type(8)));
typedef unsigned short u16x8 __attribute__((ext_vector_type(8)));
typedef float f32x4 __attribute__((ext_vector_type(4)));
typedef unsigned u32x4 __attribute__((ext_vector_type(4)));

#define MFMA(a, b, c) __builtin_amdgcn_mfma_f32_16x16x32_bf16(a, b, c, 0, 0, 0)

__device__ __forceinline__ unsigned short f2bfbits(float x) {
    unsigned u = __builtin_bit_cast(unsigned, x);
    u += 0x7FFFu + ((u >> 16) & 1u);           // round-to-nearest-even
    return (unsigned short)(u >> 16);
}

// HW packed f32->bf16 (RNE), no builtin on gfx950 -> inline asm
__device__ __forceinline__ unsigned cvt_pk(float lo, float hi) {
    unsigned r;
    asm("v_cvt_pk_bf16_f32 %0, %1, %2" : "=v"(r) : "v"(lo), "v"(hi));
    return r;
}

__device__ __forceinline__ bf16x8 pack8(f32x4 a, f32x4 b) {
    u32x4 t = { cvt_pk(a[0], a[1]), cvt_pk(a[2], a[3]),
                cvt_pk(b[0], b[1]), cvt_pk(b[2], b[3]) };
    return __builtin_bit_cast(bf16x8, t);
}

// ---------------------------------------------------------------------------
// Kernel 1: projections (as round 1, pack8 now uses v_cvt_pk).
// ---------------------------------------------------------------------------
__global__ __launch_bounds__(256) void proj_kernel(
    const float* __restrict__ q_data, const float* __restrict__ m_data,
    const float* __restrict__ Wq, const float* __restrict__ Wk,
    const float* __restrict__ Wv, const float* __restrict__ Wg,
    const float* __restrict__ bg,
    unsigned short* __restrict__ Qb, unsigned short* __restrict__ Kb,
    unsigned short* __restrict__ VT, float* __restrict__ gate)
{
    __shared__ unsigned short vt_lds[128][80];
    const int mat   = blockIdx.x >> 7;
    const int mtile = blockIdx.x & 127;
    const int wave  = threadIdx.x >> 6;
    const int lane  = threadIdx.x & 63;
    const int r16 = lane & 15, g = lane >> 4;
    const int rowbase = mtile * 64 + wave * 16;

    const float* src = (mat == 1 || mat == 2) ? m_data : q_data;
    const float* W   = (mat == 0) ? Wq : (mat == 1) ? Wk : (mat == 2) ? Wv : Wg;

    bf16x8 afrag[4];
    {
        const float* arow = src + (size_t)(rowbase + r16) * 128;
        #pragma unroll
        for (int kk = 0; kk < 4; ++kk) {
            f32x4 lo = *(const f32x4*)(arow + kk * 32 + g * 8);
            f32x4 hi = *(const f32x4*)(arow + kk * 32 + g * 8 + 4);
            afrag[kk] = pack8(lo, hi);
        }
    }

    f32x4 acc[8];
    #pragma unroll
    for (int n0 = 0; n0 < 8; ++n0) {
        f32x4 a = {0.f, 0.f, 0.f, 0.f};
        #pragma unroll
        for (int kk = 0; kk < 4; ++kk) {
            f32x4 lo, hi;
            #pragma unroll
            for (int i = 0; i < 4; ++i) {
                lo[i] = W[(size_t)(kk * 32 + g * 8 + i) * 128 + n0 * 16 + r16];
                hi[i] = W[(size_t)(kk * 32 + g * 8 + 4 + i) * 128 + n0 * 16 + r16];
            }
            a = MFMA(afrag[kk], pack8(lo, hi), a);
        }
        acc[n0] = a;
    }

    if (mat <= 1) {
        unsigned short* dst = (mat == 0) ? Qb : Kb;
        #pragma unroll
        for (int n0 = 0; n0 < 8; ++n0) {
            int n = n0 * 16 + r16, h = n >> 5, d = n & 31;
            #pragma unroll
            for (int i = 0; i < 4; ++i) {
                int grow = rowbase + 4 * g + i;
                int bb = grow >> 11, ns = grow & 2047;
                dst[(size_t)(bb * 4 + h) * 65536 + (size_t)ns * 32 + d] =
                    f2bfbits(acc[n0][i]);
            }
        }
    } else if (mat == 2) {
        #pragma unroll
        for (int n0 = 0; n0 < 8; ++n0) {
            int n = n0 * 16 + r16;
            #pragma unroll
            for (int i = 0; i < 4; ++i)
                vt_lds[n][wave * 16 + 4 * g + i] = f2bfbits(acc[n0][i]);
        }
        __syncthreads();
        int bb = rowbase >> 11;
        int nsbase = (mtile * 64) & 2047;
        #pragma unroll
        for (int it = 0; it < 4; ++it) {
            int idx = (threadIdx.x + it * 256) * 8;
            int n = idx >> 6, mm = idx & 63;
            u16x8 v = *(const u16x8*)&vt_lds[n][mm];
            *(u16x8*)(VT + (size_t)(bb * 128 + n) * 2048 + nsbase + mm) = v;
        }
    } else {
        #pragma unroll
        for (int n0 = 0; n0 < 8; ++n0) {
            int n = n0 * 16 + r16;
            float bgv = bg[n];
            #pragma unroll
            for (int i = 0; i < 4; ++i) {
                int grow = rowbase + 4 * g + i;
                float x = acc[n0][i] + bgv;
                gate[(size_t)grow * 128 + n] = 1.0f / (1.0f + __expf(-x));
            }
        }
    }
}

// ---------------------------------------------------------------------------
// Kernel 2: flash attention + gate + output GEMM.
// 512 blocks (XCD-swizzled) x 256 threads (4 waves = 4 heads, one 16-q tile).
// K-row permutation sigma(t*16+4g+i) = (t&1)*32+(t>>1)*4+8g+i makes the
// swapped-QK^T output layout exactly the swapped-PV B-fragment layout:
// P never leaves registers (no LDS, no shuffles). acc/alpha/l are lane-local.
// bias+nbias+K register-prefetched one iteration ahead (double-buffered).
// ---------------------------------------------------------------------------
__global__ __launch_bounds__(256, 2) void attn_kernel(
    const unsigned short* __restrict__ Qb, const unsigned short* __restrict__ Kb,
    const unsigned short* __restrict__ VT, const float* __restrict__ gate,
    const float* __restrict__ bias, const float* __restrict__ nbias,
    const float* __restrict__ Wo, const float* __restrict__ bo,
    float* __restrict__ out)
{
    __shared__ unsigned short wa_lds[16][136];

    // XCD-aware bijective swizzle: 512 blocks -> 8 XCDs x 64 contiguous
    const int linear = (blockIdx.x & 7) * 64 + (blockIdx.x >> 3);
    const int b  = linear >> 7;
    const int qb = (linear & 127) * 16;

    const int h    = threadIdx.x >> 6;
    const int lane = threadIdx.x & 63;
    const int q16 = lane & 15, g = lane >> 4;

    const size_t bh = (size_t)(b * 4 + h);
    const unsigned short* Qp = Qb + bh * 65536;
    const unsigned short* Kp = Kb + bh * 65536;
    const unsigned short* Vp = VT + bh * 65536;
    bf16x8 qfrag = *(const bf16x8*)(Qp + (size_t)(qb + q16) * 32 + g * 8);
    const float* brow = bias  + ((size_t)b * 2048 + qb + q16) * 2048;
    const float* nrow = nbias + ((size_t)h * 2048 + qb + q16) * 2048;

    // permuted K-row index for the QK^T A-fragment (lane&15 = row slot)
    const int krow = ((q16 >> 2) << 3) + (q16 & 3);

    float m = -1e30f, ls = 0.f;
    f32x4 acc0 = {0, 0, 0, 0}, acc1 = {0, 0, 0, 0};

    f32x4 bbA[4], nnA[4], bbB[4], nnB[4];
    bf16x8 kfA[4], kfB[4];

    auto stage = [&](f32x4 (&bb)[4], f32x4 (&nn)[4], bf16x8 (&kf)[4], int it) {
        if (it >= 32) return;
        const int kb = it * 64;
        const int toff[4] = {0, 32, 4, 36};
        #pragma unroll
        for (int t = 0; t < 4; ++t) {
            bb[t] = *(const f32x4*)(brow + kb + toff[t] + g * 8);
            nn[t] = *(const f32x4*)(nrow + kb + toff[t] + g * 8);
            kf[t] = *(const bf16x8*)(Kp + (size_t)(kb + toff[t] + krow) * 32 + g * 8);
        }
    };

    auto body = [&](f32x4 (&bb)[4], f32x4 (&nn)[4], bf16x8 (&kf)[4], int it) {
        const int kb = it * 64;
        // V A-fragments (L2-resident) — independent, issue early
        bf16x8 vf00 = *(const bf16x8*)(Vp + (size_t)q16 * 2048        + kb      + g * 8);
        bf16x8 vf10 = *(const bf16x8*)(Vp + (size_t)(16 + q16) * 2048 + kb      + g * 8);
        bf16x8 vf01 = *(const bf16x8*)(Vp + (size_t)q16 * 2048        + kb + 32 + g * 8);
        bf16x8 vf11 = *(const bf16x8*)(Vp + (size_t)(16 + q16) * 2048 + kb + 32 + g * 8);

        // QK^T (swapped, permuted rows): s[t][i] = S[kb + toff[t]+8g+i][q16]
        f32x4 s[4];
        #pragma unroll
        for (int t = 0; t < 4; ++t) {
            f32x4 z = {0, 0, 0, 0};
            s[t] = MFMA(kf[t], qfrag, z);
        }
        #pragma unroll
        for (int t = 0; t < 4; ++t) s[t] += bb[t] + nn[t];

        // online softmax (column reduce over the 4 g-lanes of this q16)
        float mx = s[0][0];
        #pragma unroll
        for (int t = 0; t < 4; ++t)
            mx = fmaxf(mx, fmaxf(fmaxf(s[t][0], s[t][1]), fmaxf(s[t][2], s[t][3])));
        mx = fmaxf(mx, __shfl_xor(mx, 16));
        mx = fmaxf(mx, __shfl_xor(mx, 32));
        float m_new = fmaxf(m, mx);
        float alpha = __expf(m - m_new);
        float psum = 0.f;
        #pragma unroll
        for (int t = 0; t < 4; ++t) {
            #pragma unroll
            for (int i = 0; i < 4; ++i) {
                float pv = __expf(s[t][i] - m_new);
                s[t][i] = pv;
                psum += pv;
            }
        }
        psum += __shfl_xor(psum, 16);
        psum += __shfl_xor(psum, 32);
        ls = ls * alpha + psum;
        m = m_new;

        // pack P -> swapped-PV B-fragments (pure register, sigma-aligned)
        unsigned u0 = cvt_pk(s[0][0], s[0][1]), u1 = cvt_pk(s[0][2], s[0][3]);
        unsigned u2 = cvt_pk(s[1][0], s[1][1]), u3 = cvt_pk(s[1][2], s[1][3]);
        unsigned u4 = cvt_pk(s[2][0], s[2][1]), u5 = cvt_pk(s[2][2], s[2][3]);
        unsigned u6 = cvt_pk(s[3][0], s[3][1]), u7 = cvt_pk(s[3][2], s[3][3]);
        u32x4 c0 = {u0, u1, u4, u5};   // k = kb + 8g + 0..7        (c-block 0)
        u32x4 c1 = {u2, u3, u6, u7};   // k = kb + 32 + 8g + 0..7   (c-block 1)
        bf16x8 p0 = __builtin_bit_cast(bf16x8, c0);
        bf16x8 p1 = __builtin_bit_cast(bf16x8, c1);

        acc0 *= alpha;
        acc1 *= alpha;
        acc0 = MFMA(vf00, p0, acc0);   // lane: out[q16][d=4g+i]
        acc1 = MFMA(vf10, p0, acc1);   // lane: out[q16][d=16+4g+i]
        acc0 = MFMA(vf01, p1, acc0);
        acc1 = MFMA(vf11, p1, acc1);
    };

    stage(bbA, nnA, kfA, 0);
    #pragma unroll 1
    for (int it = 0; it < 32; it += 2) {
        stage(bbB, nnB, kfB, it + 1);
        body(bbA, nnA, kfA, it);
        stage(bbA, nnA, kfA, it + 2);
        body(bbB, nnB, kfB, it + 1);
    }

    // ---- epilogue: /l, gate (all lane-local), stage bf16 wa tile ----
    float invL = 1.0f / ls;
    const float* grow = gate + ((size_t)b * 2048 + qb + q16) * 128 + h * 32;
    f32x4 g0 = *(const f32x4*)(grow + 4 * g);
    f32x4 g1 = *(const f32x4*)(grow + 16 + 4 * g);
    unsigned w0 = cvt_pk(acc0[0] * invL * g0[0], acc0[1] * invL * g0[1]);
    unsigned w1 = cvt_pk(acc0[2] * invL * g0[2], acc0[3] * invL * g0[3]);
    unsigned w2 = cvt_pk(acc1[0] * invL * g1[0], acc1[1] * invL * g1[1]);
    unsigned w3 = cvt_pk(acc1[2] * invL * g1[2], acc1[3] * invL * g1[3]);
    {
        uint2 t0; t0.x = w0; t0.y = w1;
        uint2 t1; t1.x = w2; t1.y = w3;
        *(uint2*)&wa_lds[q16][h * 32 + 4 * g]      = t0;
        *(uint2*)&wa_lds[q16][h * 32 + 16 + 4 * g] = t1;
    }
    __syncthreads();

    // ---- out = wa @ Wo + bo; wave h computes cols [32h, 32h+32) ----
    f32x4 o0 = {0, 0, 0, 0}, o1 = {0, 0, 0, 0};
    #pragma unroll
    for (int kk = 0; kk < 4; ++kk) {
        bf16x8 a = *(const bf16x8*)&wa_lds[q16][kk * 32 + g * 8];
        f32x4 l0, h0, l1, h1;
        #pragma unroll
        for (int i = 0; i < 4; ++i) {
            int k0 = kk * 32 + g * 8 + i;
            int k1 = k0 + 4;
            l0[i] = Wo[(size_t)k0 * 128 + h * 32 + q16];
            h0[i] = Wo[(size_t)k1 * 128 + h * 32 + q16];
            l1[i] = Wo[(size_t)k0 * 128 + h * 32 + 16 + q16];
            h1[i] = Wo[(size_t)k1 * 128 + h * 32 + 16 + q16];
        }
        o0 = MFMA(a, pack8(l0, h0), o0);
        o1 = MFMA(a, pack8(l1, h1), o1);
    }
    float bo0 = bo[h * 32 + q16], bo1 = bo[h * 32 + 16 + q16];
    #pragma unroll
    for (int i = 0; i < 4; ++i) {
        int row = qb + 4 * g + i;
        out[((size_t)b * 2048 + row) * 128 + h * 32 + q16]      = o0[i] + bo0;
        out[((size_t)b * 2048 + row) * 128 + h * 32 + 16 + q16] = o1[i] + bo1;
    }
}

// ---------------------------------------------------------------------------
extern "C" void kernel_launch(void* const* d_in, const int* in_sizes, int n_in,
                              void* d_out, int out_size, void* d_ws, size_t ws_size,
                              hipStream_t stream)
{
    const float* q_data = (const float*)d_in[0];
    const float* m_data = (const float*)d_in[1];
    const float* bias   = (const float*)d_in[2];
    const float* nbias  = (const float*)d_in[3];
    const float* Wq     = (const float*)d_in[4];
    const float* Wk     = (const float*)d_in[5];
    const float* Wv     = (const float*)d_in[6];
    const float* Wg     = (const float*)d_in[7];
    const float* bg     = (const float*)d_in[8];
    const float* Wo     = (const float*)d_in[9];
    const float* bo     = (const float*)d_in[10];
    float* out = (float*)d_out;

    unsigned short* Qb = (unsigned short*)d_ws;          // 1M bf16 = 2MB
    unsigned short* Kb = Qb + (1 << 20);
    unsigned short* VT = Kb + (1 << 20);
    float* gate = (float*)(VT + (1 << 20));              // 4MB

    proj_kernel<<<dim3(512), dim3(256), 0, stream>>>(
        q_data, m_data, Wq, Wk, Wv, Wg, bg, Qb, Kb, VT, gate);
    attn_kernel<<<dim3(512), dim3(256), 0, stream>>>(
        Qb, Kb, VT, gate, bias, nbias, Wo, bo, out);
}

// Round 4
// 89.780 us; speedup vs baseline: 1.5261x; 1.3242x over previous
//
#include <hip/hip_runtime.h>
#include <cstdint>
#include <cstddef>

typedef __bf16 bf16x8 __attribute__((ext_vector_type(8)));
typedef unsigned short u16x8 __attribute__((ext_vector_type(8)));
typedef float f32x4 __attribute__((ext_vector_type(4)));
typedef unsigned u32x4 __attribute__((ext_vector_type(4)));

#define MFMA(a, b, c) __builtin_amdgcn_mfma_f32_16x16x32_bf16(a, b, c, 0, 0, 0)

__device__ __forceinline__ unsigned short f2bfbits(float x) {
    unsigned u = __builtin_bit_cast(unsigned, x);
    u += 0x7FFFu + ((u >> 16) & 1u);           // round-to-nearest-even
    return (unsigned short)(u >> 16);
}

// HW packed f32->bf16 (RNE), no builtin on gfx950 -> inline asm
__device__ __forceinline__ unsigned cvt_pk(float lo, float hi) {
    unsigned r;
    asm("v_cvt_pk_bf16_f32 %0, %1, %2" : "=v"(r) : "v"(lo), "v"(hi));
    return r;
}

__device__ __forceinline__ bf16x8 pack8(f32x4 a, f32x4 b) {
    u32x4 t = { cvt_pk(a[0], a[1]), cvt_pk(a[2], a[3]),
                cvt_pk(b[0], b[1]), cvt_pk(b[2], b[3]) };
    return __builtin_bit_cast(bf16x8, t);
}

// async global->LDS DMA, 16B per lane. LDS dest = wave-uniform base + lane*16;
// global src is per-lane.
__device__ __forceinline__ void gl_lds16(const void* g, void* l) {
    __builtin_amdgcn_global_load_lds(
        (const __attribute__((address_space(1))) unsigned int*)g,
        (__attribute__((address_space(3))) unsigned int*)l, 16, 0, 0);
}

// ---------------------------------------------------------------------------
// Kernel 1: projections (unchanged; passed rounds 1-3).
// ---------------------------------------------------------------------------
__global__ __launch_bounds__(256) void proj_kernel(
    const float* __restrict__ q_data, const float* __restrict__ m_data,
    const float* __restrict__ Wq, const float* __restrict__ Wk,
    const float* __restrict__ Wv, const float* __restrict__ Wg,
    const float* __restrict__ bg,
    unsigned short* __restrict__ Qb, unsigned short* __restrict__ Kb,
    unsigned short* __restrict__ VT, float* __restrict__ gate)
{
    __shared__ unsigned short vt_lds[128][80];
    const int mat   = blockIdx.x >> 7;
    const int mtile = blockIdx.x & 127;
    const int wave  = threadIdx.x >> 6;
    const int lane  = threadIdx.x & 63;
    const int r16 = lane & 15, g = lane >> 4;
    const int rowbase = mtile * 64 + wave * 16;

    const float* src = (mat == 1 || mat == 2) ? m_data : q_data;
    const float* W   = (mat == 0) ? Wq : (mat == 1) ? Wk : (mat == 2) ? Wv : Wg;

    bf16x8 afrag[4];
    {
        const float* arow = src + (size_t)(rowbase + r16) * 128;
        #pragma unroll
        for (int kk = 0; kk < 4; ++kk) {
            f32x4 lo = *(const f32x4*)(arow + kk * 32 + g * 8);
            f32x4 hi = *(const f32x4*)(arow + kk * 32 + g * 8 + 4);
            afrag[kk] = pack8(lo, hi);
        }
    }

    f32x4 acc[8];
    #pragma unroll
    for (int n0 = 0; n0 < 8; ++n0) {
        f32x4 a = {0.f, 0.f, 0.f, 0.f};
        #pragma unroll
        for (int kk = 0; kk < 4; ++kk) {
            f32x4 lo, hi;
            #pragma unroll
            for (int i = 0; i < 4; ++i) {
                lo[i] = W[(size_t)(kk * 32 + g * 8 + i) * 128 + n0 * 16 + r16];
                hi[i] = W[(size_t)(kk * 32 + g * 8 + 4 + i) * 128 + n0 * 16 + r16];
            }
            a = MFMA(afrag[kk], pack8(lo, hi), a);
        }
        acc[n0] = a;
    }

    if (mat <= 1) {
        unsigned short* dst = (mat == 0) ? Qb : Kb;
        #pragma unroll
        for (int n0 = 0; n0 < 8; ++n0) {
            int n = n0 * 16 + r16, h = n >> 5, d = n & 31;
            #pragma unroll
            for (int i = 0; i < 4; ++i) {
                int grow = rowbase + 4 * g + i;
                int bb = grow >> 11, ns = grow & 2047;
                dst[(size_t)(bb * 4 + h) * 65536 + (size_t)ns * 32 + d] =
                    f2bfbits(acc[n0][i]);
            }
        }
    } else if (mat == 2) {
        #pragma unroll
        for (int n0 = 0; n0 < 8; ++n0) {
            int n = n0 * 16 + r16;
            #pragma unroll
            for (int i = 0; i < 4; ++i)
                vt_lds[n][wave * 16 + 4 * g + i] = f2bfbits(acc[n0][i]);
        }
        __syncthreads();
        int bb = rowbase >> 11;
        int nsbase = (mtile * 64) & 2047;
        #pragma unroll
        for (int it = 0; it < 4; ++it) {
            int idx = (threadIdx.x + it * 256) * 8;
            int n = idx >> 6, mm = idx & 63;
            u16x8 v = *(const u16x8*)&vt_lds[n][mm];
            *(u16x8*)(VT + (size_t)(bb * 128 + n) * 2048 + nsbase + mm) = v;
        }
    } else {
        #pragma unroll
        for (int n0 = 0; n0 < 8; ++n0) {
            int n = n0 * 16 + r16;
            float bgv = bg[n];
            #pragma unroll
            for (int i = 0; i < 4; ++i) {
                int grow = rowbase + 4 * g + i;
                float x = acc[n0][i] + bgv;
                gate[(size_t)grow * 128 + n] = 1.0f / (1.0f + __expf(-x));
            }
        }
    }
}

// ---------------------------------------------------------------------------
// Kernel 2: flash attention + gate + output GEMM.
// 512 blocks (natural order: b*128+qt -> same-qt blocks share an XCD for
// nbias L2 reuse) x 256 threads (4 waves = 4 heads, one 16-q tile).
// All loop VMEM is global_load_lds DMA (bias, nbias, K, V), double-buffered
// LDS (KB_STEP=32, 56KB total), raw s_barrier + per-wave counted vmcnt
// (never drains). K stored sigma-permuted so P stays in registers;
// bias/nbias XOR-swizzled both-sides (pre-swizzled global source).
// ---------------------------------------------------------------------------
__global__ __launch_bounds__(256, 2) void attn_kernel(
    const unsigned short* __restrict__ Qb, const unsigned short* __restrict__ Kb,
    const unsigned short* __restrict__ VT, const float* __restrict__ gate,
    const float* __restrict__ bias, const float* __restrict__ nbias,
    const float* __restrict__ Wo, const float* __restrict__ bo,
    float* __restrict__ out)
{
    __shared__ float biasT[2][16][32];               // 4KB
    __shared__ float nbT[2][4][16][32];              // 16KB
    __shared__ unsigned short kT[2][4][2][16][32];   // 16KB
    __shared__ unsigned short vT[2][4][32][32];      // 16KB
    __shared__ unsigned short wa_lds[16][136];       // 4.25KB

    const int b  = blockIdx.x >> 7;
    const int qb = (blockIdx.x & 127) * 16;
    const int h    = threadIdx.x >> 6;
    const int lane = threadIdx.x & 63;
    const int q16 = lane & 15, g = lane >> 4;

    const size_t bh = (size_t)(b * 4 + h);
    const unsigned short* Qp = Qb + bh * 65536;
    const unsigned short* Kp = Kb + bh * 65536;
    const unsigned short* Vp = VT + bh * 65536;
    bf16x8 qfrag = *(const bf16x8*)(Qp + (size_t)(qb + q16) * 32 + g * 8);

    // staging lane decompositions
    const int ls8 = lane >> 3, lc8 = lane & 7;       // bias/nbias chunks
    const int rho = lane >> 2, l4 = lane & 3;        // K/V chunks
    const int krow_l = ((rho >> 2) << 3) + (rho & 3);   // sigma permutation

    const float* bias_b = bias  + ((size_t)b * 2048 + qb) * 2048;
    const float* nb_h   = nbias + ((size_t)h * 2048 + qb) * 2048;

    float m = -1e30f, lsum = 0.f;
    f32x4 acc0 = {0, 0, 0, 0}, acc1 = {0, 0, 0, 0};

    auto stage = [&](int it) {
        const int bf = it & 1;
        const int kb = it * 32;
        // nbias: 2 chunks (rows 8c+ls8), swizzled source
        #pragma unroll
        for (int c = 0; c < 2; ++c) {
            int row = 8 * c + ls8;
            int coldw = (lc8 * 4) ^ ((row & 7) << 2);
            gl_lds16(nb_h + (size_t)row * 2048 + kb + coldw,
                     (char*)&nbT[bf][h][0][0] + c * 1024);
        }
        // bias: 2 chunks staged by waves 0,1
        if (h < 2) {
            int row = 8 * h + ls8;
            int coldw = (lc8 * 4) ^ ((row & 7) << 2);
            gl_lds16(bias_b + (size_t)row * 2048 + kb + coldw,
                     (char*)&biasT[bf][0][0] + h * 1024);
        }
        // K: 2 chunks, sigma-permuted rows (slot rho holds row kb+4t+krow(rho))
        #pragma unroll
        for (int t = 0; t < 2; ++t)
            gl_lds16(Kp + (size_t)(kb + 4 * t + krow_l) * 32 + l4 * 8,
                     (char*)&kT[bf][h][t][0][0]);
        // V: 2 chunks (d rows 16j+rho)
        #pragma unroll
        for (int j = 0; j < 2; ++j)
            gl_lds16(Vp + (size_t)(16 * j + rho) * 2048 + kb + l4 * 8,
                     (char*)&vT[bf][h][16 * j][0]);
    };

    stage(0);

    #pragma unroll 2
    for (int it = 0; it < 64; ++it) {
        const int bf = it & 1;
        if (it < 63) {
            stage(it + 1);
            // stage(it) done; stage(it+1)'s 7/6 loads stay in flight
            if (h < 2) { asm volatile("s_waitcnt vmcnt(7)" ::: "memory"); }
            else       { asm volatile("s_waitcnt vmcnt(6)" ::: "memory"); }
        } else {
            asm volatile("s_waitcnt vmcnt(0)" ::: "memory");
        }
        __builtin_amdgcn_sched_barrier(0);
        __builtin_amdgcn_s_barrier();            // tile it visible to all waves

        // ---- LDS -> regs (swizzled reads for bias/nbias) ----
        f32x4 bb[2], nn[2];
        #pragma unroll
        for (int t = 0; t < 2; ++t) {
            int off = q16 * 128 + ((t * 16 + g * 32) ^ ((q16 & 7) << 4));
            bb[t] = *(const f32x4*)((const char*)&biasT[bf][0][0] + off);
            nn[t] = *(const f32x4*)((const char*)&nbT[bf][h][0][0] + off);
        }
        bf16x8 kf0 = *(const bf16x8*)((const char*)&kT[bf][h][0][0][0] + q16 * 64 + g * 16);
        bf16x8 kf1 = *(const bf16x8*)((const char*)&kT[bf][h][1][0][0] + q16 * 64 + g * 16);
        bf16x8 vf0 = *(const bf16x8*)((const char*)&vT[bf][h][q16][0] + g * 16);
        bf16x8 vf1 = *(const bf16x8*)((const char*)&vT[bf][h][16 + q16][0] + g * 16);
        asm volatile("s_waitcnt lgkmcnt(0)" ::: "memory");
        __builtin_amdgcn_sched_barrier(0);
        __builtin_amdgcn_s_barrier();            // buf[bf] free for it+2's stage

        // ---- compute (register-only) ----
        f32x4 z = {0, 0, 0, 0};
        f32x4 s0 = MFMA(kf0, qfrag, z);          // s0[i] = S[kb+8g+i][q16]
        f32x4 s1 = MFMA(kf1, qfrag, z);          // s1[i] = S[kb+4+8g+i][q16]
        s0 += bb[0] + nn[0];
        s1 += bb[1] + nn[1];

        float mx = fmaxf(fmaxf(fmaxf(s0[0], s0[1]), fmaxf(s0[2], s0[3])),
                         fmaxf(fmaxf(s1[0], s1[1]), fmaxf(s1[2], s1[3])));
        mx = fmaxf(mx, __shfl_xor(mx, 16));
        mx = fmaxf(mx, __shfl_xor(mx, 32));
        float m_new = fmaxf(m, mx);
        float alpha = __expf(m - m_new);
        float ps = 0.f;
        #pragma unroll
        for (int i = 0; i < 4; ++i) { s0[i] = __expf(s0[i] - m_new); ps += s0[i]; }
        #pragma unroll
        for (int i = 0; i < 4; ++i) { s1[i] = __expf(s1[i] - m_new); ps += s1[i]; }
        ps += __shfl_xor(ps, 16);
        ps += __shfl_xor(ps, 32);
        lsum = lsum * alpha + ps;
        m = m_new;

        // P -> PV B-fragment (register-only, sigma-aligned)
        u32x4 pc = { cvt_pk(s0[0], s0[1]), cvt_pk(s0[2], s0[3]),
                     cvt_pk(s1[0], s1[1]), cvt_pk(s1[2], s1[3]) };
        bf16x8 p = __builtin_bit_cast(bf16x8, pc);

        acc0 *= alpha;
        acc1 *= alpha;
        acc0 = MFMA(vf0, p, acc0);               // lane: out[q16][d=4g+i]
        acc1 = MFMA(vf1, p, acc1);               // lane: out[q16][d=16+4g+i]
    }

    // ---- epilogue: /l, gate (lane-local), stage bf16 wa tile ----
    float invL = 1.0f / lsum;
    const float* grow = gate + ((size_t)b * 2048 + qb + q16) * 128 + h * 32;
    f32x4 g0 = *(const f32x4*)(grow + 4 * g);
    f32x4 g1 = *(const f32x4*)(grow + 16 + 4 * g);
    unsigned w0 = cvt_pk(acc0[0] * invL * g0[0], acc0[1] * invL * g0[1]);
    unsigned w1 = cvt_pk(acc0[2] * invL * g0[2], acc0[3] * invL * g0[3]);
    unsigned w2 = cvt_pk(acc1[0] * invL * g1[0], acc1[1] * invL * g1[1]);
    unsigned w3 = cvt_pk(acc1[2] * invL * g1[2], acc1[3] * invL * g1[3]);
    {
        uint2 t0; t0.x = w0; t0.y = w1;
        uint2 t1; t1.x = w2; t1.y = w3;
        *(uint2*)&wa_lds[q16][h * 32 + 4 * g]      = t0;
        *(uint2*)&wa_lds[q16][h * 32 + 16 + 4 * g] = t1;
    }
    __syncthreads();

    // ---- out = wa @ Wo + bo; wave h computes cols [32h, 32h+32) ----
    f32x4 o0 = {0, 0, 0, 0}, o1 = {0, 0, 0, 0};
    #pragma unroll
    for (int kk = 0; kk < 4; ++kk) {
        bf16x8 a = *(const bf16x8*)&wa_lds[q16][kk * 32 + g * 8];
        f32x4 l0, h0, l1, h1;
        #pragma unroll
        for (int i = 0; i < 4; ++i) {
            int k0 = kk * 32 + g * 8 + i;
            int k1 = k0 + 4;
            l0[i] = Wo[(size_t)k0 * 128 + h * 32 + q16];
            h0[i] = Wo[(size_t)k1 * 128 + h * 32 + q16];
            l1[i] = Wo[(size_t)k0 * 128 + h * 32 + 16 + q16];
            h1[i] = Wo[(size_t)k1 * 128 + h * 32 + 16 + q16];
        }
        o0 = MFMA(a, pack8(l0, h0), o0);
        o1 = MFMA(a, pack8(l1, h1), o1);
    }
    float bo0 = bo[h * 32 + q16], bo1 = bo[h * 32 + 16 + q16];
    #pragma unroll
    for (int i = 0; i < 4; ++i) {
        int row = qb + 4 * g + i;
        out[((size_t)b * 2048 + row) * 128 + h * 32 + q16]      = o0[i] + bo0;
        out[((size_t)b * 2048 + row) * 128 + h * 32 + 16 + q16] = o1[i] + bo1;
    }
}

// ---------------------------------------------------------------------------
extern "C" void kernel_launch(void* const* d_in, const int* in_sizes, int n_in,
                              void* d_out, int out_size, void* d_ws, size_t ws_size,
                              hipStream_t stream)
{
    const float* q_data = (const float*)d_in[0];
    const float* m_data = (const float*)d_in[1];
    const float* bias   = (const float*)d_in[2];
    const float* nbias  = (const float*)d_in[3];
    const float* Wq     = (const float*)d_in[4];
    const float* Wk     = (const float*)d_in[5];
    const float* Wv     = (const float*)d_in[6];
    const float* Wg     = (const float*)d_in[7];
    const float* bg     = (const float*)d_in[8];
    const float* Wo     = (const float*)d_in[9];
    const float* bo     = (const float*)d_in[10];
    float* out = (float*)d_out;

    unsigned short* Qb = (unsigned short*)d_ws;          // 1M bf16 = 2MB
    unsigned short* Kb = Qb + (1 << 20);
    unsigned short* VT = Kb + (1 << 20);
    float* gate = (float*)(VT + (1 << 20));              // 4MB

    proj_kernel<<<dim3(512), dim3(256), 0, stream>>>(
        q_data, m_data, Wq, Wk, Wv, Wg, bg, Qb, Kb, VT, gate);
    attn_kernel<<<dim3(512), dim3(256), 0, stream>>>(
        Qb, Kb, VT, gate, bias, nbias, Wo, bo, out);
}